// Round 12
// baseline (444.512 us; speedup 1.0000x reference)
//
#include <hip/hip_runtime.h>
#include <hip/hip_bf16.h>
#include <hip/hip_cooperative_groups.h>
#include <cstdint>
#include <cstddef>

namespace cg = cooperative_groups;

#define NNODES 50000
#define NEDGES 800000
#define NB     256                         // coop grid = 1 block/CU
// deg hist: blocks 0..63
#define DHB    64
#define DHC    12500                       // 64*12500 = 800000
// sort pass 1: blocks 64..255 -> 192 chunks
#define GA1    192
#define CHUNK1 4167                        // 192*4167 = 800064 >= 800000
#define GH1TOT (256 * GA1)                 // 49152 = 192 scan-chunks of 256
// sort pass 2: 1024 wave-chunks (stable)
#define SCB2   1024
#define C2     782                         // 1024*782 = 800768 >= 800000
#define GH2TOT (256 * SCB2)                // 262144 = 1024 scan-chunks of 256

typedef unsigned short u16;
typedef unsigned int u32;
typedef short bfrag8 __attribute__((ext_vector_type(8)));
typedef float f32x4 __attribute__((ext_vector_type(4)));

__device__ __forceinline__ u16 f2bf(float f) {
    union { float f; uint32_t i; } v; v.f = f;
    uint32_t r = (v.i + 0x7FFFu + ((v.i >> 16) & 1u)) >> 16;
    return (u16)r;
}
__device__ __forceinline__ float bflo(u32 p) { union { uint32_t i; float f; } v; v.i = p << 16; return v.f; }
__device__ __forceinline__ float bfhi(u32 p) { union { uint32_t i; float f; } v; v.i = p & 0xFFFF0000u; return v.f; }

// ============ ONE cooperative kernel: deg hist + 2-pass sort + bounds ============
__global__ void build_graph(const float* __restrict__ W1, const float* __restrict__ W2,
                            u16* __restrict__ P1w, u16* __restrict__ P2w,
                            const int* __restrict__ src, const int* __restrict__ dst,
                            u32* __restrict__ histg, u32* __restrict__ gh1,
                            int* __restrict__ scan1, int* __restrict__ part1,
                            u32* __restrict__ sbuf, u32* __restrict__ gh2,
                            int* __restrict__ scan2g, int* __restrict__ part2,
                            u32* __restrict__ sorted, int* __restrict__ deg,
                            int* __restrict__ rp, int nE) {
    __shared__ __align__(16) u32 ls[25088];   // 100.3 KB union
    cg::grid_group grid = cg::this_grid();
    const int b = blockIdx.x, t = threadIdx.x;

    // ---- P0: deg hist (blocks 0..63) | pass-1 hist + weight prep (blocks 64..255) ----
    if (b < DHB) {
        for (int j = t; j < NNODES / 2; j += 256) ls[j] = 0;
        __syncthreads();
        int beg = b * DHC, end = min(beg + DHC, nE);
        for (int i = beg + t; i < end; i += 256) {
            u32 n = (u32)src[i];
            atomicAdd(&ls[n >> 1], 1u << ((n & 1) * 16));
        }
        __syncthreads();
        u32* out = histg + (size_t)b * (NNODES / 2);
        for (int j = t; j < NNODES / 2; j += 256) out[j] = ls[j];
    } else {
        int c = b - DHB;
        ls[t] = 0;
        __syncthreads();
        int beg = c * CHUNK1, end = min(beg + CHUNK1, nE);
        for (int i = beg + t; i < end; i += 256)
            atomicAdd(&ls[(u32)dst[i] & 255u], 1);
        __syncthreads();
        gh1[t * GA1 + c] = ls[t];
        if (b < 192) {                       // W1: 128 blocks x 256 = 32768 exact
            int i = (b - 64) * 256 + t;
            int k = i >> 7, n = i & 127;
            P1w[((((k >> 3) << 7) + n) << 3) | (k & 7)] = f2bf(W1[i]);
        } else if (b < 224) {                // W2: 32 blocks x 256 = 8192 exact
            int i = (b - 192) * 256 + t;
            int k = i >> 6, n = i & 63;
            P2w[((((k >> 3) << 6) + n) << 3) | (k & 7)] = f2bf(W2[i]);
        }
    }
    grid.sync();

    // ---- P1: scan gh1 (192 chunks, blocks 0..191) + deg reduce (all blocks) ----
    if (b < GA1) {
        int* sd = (int*)ls;
        int gi = b * 256 + t;
        int v = (int)gh1[gi];
        sd[t] = v;
        __syncthreads();
        #pragma unroll
        for (int o = 1; o < 256; o <<= 1) {
            int add = (t >= o) ? sd[t - o] : 0;
            __syncthreads();
            sd[t] += add;
            __syncthreads();
        }
        scan1[gi] = sd[t];
        if (t == 255) part1[b] = sd[255];
    }
    {
        int n = b * 196 + t;
        if (t < 196 && n < NNODES) {
            int s = 0;
            #pragma unroll 4
            for (int bb = 0; bb < DHB; bb++)
                s += (int)((histg[(size_t)bb * (NNODES / 2) + (n >> 1)] >> ((n & 1) * 16)) & 0xFFFFu);
            deg[n] = s;
        }
    }
    grid.sync();

    // ---- P2: pass-1 scatter (blocks 64..255, same chunks as P0) ----
    if (b >= DHB) {
        int c = b - DHB;
        int* sd    = (int*)ls;              // 256
        int* offsL = (int*)(ls + 256);      // 192
        u32* baseL = ls + 512;              // 256
        u32* lh    = ls + 768;              // 256
        int v = (t < GA1) ? part1[t] : 0;
        sd[t] = v;
        __syncthreads();
        #pragma unroll
        for (int o = 1; o < 256; o <<= 1) {
            int add = (t >= o) ? sd[t - o] : 0;
            __syncthreads();
            sd[t] += add;
            __syncthreads();
        }
        if (t < GA1) offsL[t] = sd[t] - v;
        __syncthreads();
        int idx = t * GA1 + c;
        baseL[t] = (u32)(scan1[idx] + offsL[idx >> 8] - (int)gh1[idx]);
        lh[t] = 0;
        __syncthreads();
        int beg = c * CHUNK1, end = min(beg + CHUNK1, nE);
        for (int i = beg + t; i < end; i += 256) {
            u32 el = ((u32)dst[i] << 16) | (u32)src[i];
            u32 d = (el >> 16) & 255u;
            u32 r = atomicAdd(&lh[d], 1);
            sbuf[baseL[d] + r] = el;
        }
    }
    grid.sync();

    // ---- P3: pass-2 histogram (1024 wave-chunks) ----
    {
        int w = t >> 6, lane = t & 63;
        int cgi = b * 4 + w;
        for (int j = lane; j < 256; j += 64) ls[w * 256 + j] = 0;
        __syncthreads();
        int beg = cgi * C2, end = min(beg + C2, nE);
        for (int i = beg + lane; i < end; i += 64)
            atomicAdd(&ls[w * 256 + (sbuf[i] >> 24)], 1);
        __syncthreads();
        for (int j = lane; j < 256; j += 64)
            gh2[j * SCB2 + cgi] = ls[w * 256 + j];
    }
    grid.sync();

    // ---- P4: scan gh2 (1024 chunks, 4 per block) ----
    {
        int* sd = (int*)ls;
        for (int gg = 0; gg < 4; gg++) {
            int g = b * 4 + gg;
            int gi = g * 256 + t;
            int v = (int)gh2[gi];
            sd[t] = v;
            __syncthreads();
            #pragma unroll
            for (int o = 1; o < 256; o <<= 1) {
                int add = (t >= o) ? sd[t - o] : 0;
                __syncthreads();
                sd[t] += add;
                __syncthreads();
            }
            scan2g[gi] = sd[t];
            if (t == 255) part2[g] = sd[255];
            __syncthreads();
        }
    }
    grid.sync();

    // ---- P5: pass-2 STABLE scatter (ballot-ranked, wave-chunk cg = b*4+w) ----
    {
        int* sd    = (int*)ls;              // 256
        int* offs2 = (int*)(ls + 256);      // 1024
        u32* run   = ls + 1280;             // 1024 = run[w*256+d]
        int v4[4]; int s = 0;
        #pragma unroll
        for (int j = 0; j < 4; j++) { v4[j] = part2[t * 4 + j]; s += v4[j]; }
        sd[t] = s;
        __syncthreads();
        #pragma unroll
        for (int o = 1; o < 256; o <<= 1) {
            int add = (t >= o) ? sd[t - o] : 0;
            __syncthreads();
            sd[t] += add;
            __syncthreads();
        }
        int bse = sd[t] - s;
        #pragma unroll
        for (int j = 0; j < 4; j++) { offs2[t * 4 + j] = bse; bse += v4[j]; }
        __syncthreads();
        int w = t >> 6, lane = t & 63;
        int cgi = b * 4 + w;
        for (int j = lane; j < 256; j += 64) {
            int idx = j * SCB2 + cgi;
            run[w * 256 + j] = (u32)(scan2g[idx] + offs2[idx >> 8] - (int)gh2[idx]);
        }
        __syncthreads();
        int beg = cgi * C2, end = min(beg + C2, nE);
        for (int i0 = beg; i0 < end; i0 += 64) {
            int i = i0 + lane;
            int active = (i < end);
            u32 el = active ? sbuf[i] : 0;
            u32 d = el >> 24;
            unsigned long long m = __ballot(active);
            #pragma unroll
            for (int bb = 0; bb < 8; bb++) {
                unsigned long long bm = __ballot(active && ((d >> bb) & 1));
                m &= ((d >> bb) & 1) ? bm : ~bm;
            }
            if (active) {
                int lanerank = __popcll(m & ((1ull << lane) - 1ull));
                int leader = __ffsll((long long)m) - 1;
                u32 base = 0;
                if (lane == leader) base = atomicAdd(&run[w * 256 + d], (u32)__popcll(m));
                base = (u32)__shfl((int)base, leader, 64);
                sorted[base + (u32)lanerank] = el;
            }
        }
    }
    grid.sync();

    // ---- P6: boundary detection -> row_ptr (grid-stride) ----
    for (int e = b * 256 + t; e < nE; e += NB * 256) {
        int k = (int)(sorted[e] >> 16);
        int kp = e ? (int)(sorted[e - 1] >> 16) : -1;
        if (k != kp)
            for (int n = kp + 1; n <= k; n++) rp[n] = e;
        if (e == nE - 1)
            for (int n = k + 1; n <= NNODES; n++) rp[n] = nE;
    }
}

// ============ dense compute (verified r8-r11) ============

template <int K, int N, bool AF32>
__global__ __launch_bounds__(256) void gemm_scaled(const void* __restrict__ A_, const u16* __restrict__ Wp,
                                                   const int* __restrict__ deg, u16* __restrict__ out, int M) {
    const int lane = threadIdx.x & 63;
    const int wave = threadIdx.x >> 6;
    const int m = lane & 15;
    const int q = lane >> 4;
    const int row0 = blockIdx.x * 64 + wave * 16;

    int rowa = row0 + m; if (rowa > M - 1) rowa = M - 1;

    constexpr int NT = N / 16;
    f32x4 acc[NT];
    #pragma unroll
    for (int t = 0; t < NT; t++) acc[t] = (f32x4){0.f, 0.f, 0.f, 0.f};

    #pragma unroll
    for (int kc = 0; kc < K; kc += 32) {
        bfrag8 af;
        if constexpr (AF32) {
            const float* ap = (const float*)A_ + (size_t)rowa * K + q * 8 + kc;
            const float4 x0 = *(const float4*)(ap);
            const float4 x1 = *(const float4*)(ap + 4);
            af[0] = (short)f2bf(x0.x); af[1] = (short)f2bf(x0.y);
            af[2] = (short)f2bf(x0.z); af[3] = (short)f2bf(x0.w);
            af[4] = (short)f2bf(x1.x); af[5] = (short)f2bf(x1.y);
            af[6] = (short)f2bf(x1.z); af[7] = (short)f2bf(x1.w);
        } else {
            const u16* ap = (const u16*)A_ + (size_t)rowa * K + q * 8 + kc;
            af = *(const bfrag8*)ap;
        }
        const u16* bbase = Wp + ((size_t)(((kc >> 3) + q) * N) + m) * 8;
        #pragma unroll
        for (int t = 0; t < NT; t++) {
            bfrag8 bf_ = *(const bfrag8*)(bbase + t * 128);
            acc[t] = __builtin_amdgcn_mfma_f32_16x16x32_bf16(af, bf_, acc[t], 0, 0, 0);
        }
    }
    #pragma unroll
    for (int r = 0; r < 4; r++) {
        int gr = row0 + q * 4 + r;
        if (gr < M) {
            int dO = deg[gr]; if (dO < 1) dO = 1;
            float s = rsqrtf((float)dO);
            #pragma unroll
            for (int t = 0; t < NT; t++)
                out[(size_t)gr * N + t * 16 + m] = f2bf(acc[t][r] * s);
        }
    }
}

__global__ __launch_bounds__(256) void gather1(const uint4* __restrict__ h, const int* __restrict__ row_ptr,
                                               const u32* __restrict__ sorted, const float* __restrict__ b1,
                                               uint4* __restrict__ h1out, int nNodes) {
    int node = (blockIdx.x * 256 + threadIdx.x) >> 4;
    int l = threadIdx.x & 15;
    if (node >= nNodes) return;
    int beg = row_ptr[node], end = row_ptr[node + 1];
    float a[8] = {0.f, 0.f, 0.f, 0.f, 0.f, 0.f, 0.f, 0.f};
    for (int e = beg; e < end; e += 4) {
        uint4 p[4];
        #pragma unroll
        for (int j = 0; j < 4; j++) {
            int ee = e + j; ee = (ee < end - 1) ? ee : end - 1;
            p[j] = h[(size_t)(sorted[ee] & 0xFFFFu) * 16 + l];
        }
        #pragma unroll
        for (int j = 0; j < 4; j++)
            if (e + j < end) {
                a[0] += bflo(p[j].x); a[1] += bfhi(p[j].x);
                a[2] += bflo(p[j].y); a[3] += bfhi(p[j].y);
                a[4] += bflo(p[j].z); a[5] += bfhi(p[j].z);
                a[6] += bflo(p[j].w); a[7] += bfhi(p[j].w);
            }
    }
    int dI = end - beg; if (dI < 1) dI = 1;
    float r = rsqrtf((float)dI);
    const float4 bA = *(const float4*)(b1 + 8 * l);
    const float4 bB = *(const float4*)(b1 + 8 * l + 4);
    float v0 = fmaxf(a[0] * r + bA.x, 0.f), v1 = fmaxf(a[1] * r + bA.y, 0.f);
    float v2 = fmaxf(a[2] * r + bA.z, 0.f), v3 = fmaxf(a[3] * r + bA.w, 0.f);
    float v4 = fmaxf(a[4] * r + bB.x, 0.f), v5 = fmaxf(a[5] * r + bB.y, 0.f);
    float v6 = fmaxf(a[6] * r + bB.z, 0.f), v7 = fmaxf(a[7] * r + bB.w, 0.f);
    uint4 o;
    o.x = ((u32)f2bf(v1) << 16) | f2bf(v0);
    o.y = ((u32)f2bf(v3) << 16) | f2bf(v2);
    o.z = ((u32)f2bf(v5) << 16) | f2bf(v4);
    o.w = ((u32)f2bf(v7) << 16) | f2bf(v6);
    h1out[(size_t)node * 16 + l] = o;
}

__global__ __launch_bounds__(256) void gather2(const uint4* __restrict__ h2, const int* __restrict__ row_ptr,
                                               const u32* __restrict__ sorted, const float* __restrict__ b2,
                                               const float* __restrict__ Wf, const float* __restrict__ bfv,
                                               float* __restrict__ logits, float* __restrict__ hidden, int nNodes) {
    int node = (blockIdx.x * 256 + threadIdx.x) >> 3;
    int l = threadIdx.x & 7;
    if (node >= nNodes) return;
    int beg = row_ptr[node], end = row_ptr[node + 1];
    float a[8] = {0.f, 0.f, 0.f, 0.f, 0.f, 0.f, 0.f, 0.f};
    for (int e = beg; e < end; e += 4) {
        uint4 p[4];
        #pragma unroll
        for (int j = 0; j < 4; j++) {
            int ee = e + j; ee = (ee < end - 1) ? ee : end - 1;
            p[j] = h2[(size_t)(sorted[ee] & 0xFFFFu) * 8 + l];
        }
        #pragma unroll
        for (int j = 0; j < 4; j++)
            if (e + j < end) {
                a[0] += bflo(p[j].x); a[1] += bfhi(p[j].x);
                a[2] += bflo(p[j].y); a[3] += bfhi(p[j].y);
                a[4] += bflo(p[j].z); a[5] += bfhi(p[j].z);
                a[6] += bflo(p[j].w); a[7] += bfhi(p[j].w);
            }
    }
    int dI = end - beg; if (dI < 1) dI = 1;
    float r = rsqrtf((float)dI);
    float v[8];
    #pragma unroll
    for (int f = 0; f < 8; f++) v[f] = a[f] * r + b2[8 * l + f];
    float4 oA = {v[0], v[1], v[2], v[3]};
    float4 oB = {v[4], v[5], v[6], v[7]};
    ((float4*)hidden)[(size_t)node * 16 + 2 * l + 0] = oA;
    ((float4*)hidden)[(size_t)node * 16 + 2 * l + 1] = oB;
    float l0 = 0.f, l1 = 0.f;
    #pragma unroll
    for (int f = 0; f < 8; f++) {
        l0 += v[f] * Wf[(8 * l + f) * 2 + 0];
        l1 += v[f] * Wf[(8 * l + f) * 2 + 1];
    }
    #pragma unroll
    for (int off = 4; off > 0; off >>= 1) {
        l0 += __shfl_down(l0, off, 8);
        l1 += __shfl_down(l1, off, 8);
    }
    if (l == 0) {
        logits[(size_t)node * 2 + 0] = l0 + bfv[0];
        logits[(size_t)node * 2 + 1] = l1 + bfv[1];
    }
}

extern "C" void kernel_launch(void* const* d_in, const int* in_sizes, int n_in,
                              void* d_out, int out_size, void* d_ws, size_t ws_size,
                              hipStream_t stream) {
    const float* x   = (const float*)d_in[0];
    const float* W1  = (const float*)d_in[1];
    const float* b1  = (const float*)d_in[2];
    const float* W2  = (const float*)d_in[3];
    const float* b2  = (const float*)d_in[4];
    const float* Wf  = (const float*)d_in[5];
    const float* bfv = (const float*)d_in[6];
    const int* src = (const int*)d_in[7];
    const int* dst = (const int*)d_in[8];

    float* out_logits = (float*)d_out;
    float* out_hidden = (float*)d_out + 2 * NNODES;

    char* ws = (char*)d_ws;
    size_t off = 0;
    auto alloc = [&](size_t bytes) { void* p = ws + off; off += (bytes + 255) & ~(size_t)255; return p; };
    u32*   gh1     = (u32*)alloc(GH1TOT * 4);
    u32*   gh2     = (u32*)alloc(GH2TOT * 4);
    int*   scan1   = (int*)alloc(GH1TOT * 4);
    int*   scan2g  = (int*)alloc(GH2TOT * 4);
    int*   part1   = (int*)alloc(256 * 4);
    int*   part2   = (int*)alloc(1024 * 4);
    u32*   sbuf    = (u32*)alloc((size_t)NEDGES * 4);
    u32*   sorted  = (u32*)alloc((size_t)NEDGES * 4);
    u32*   histg   = (u32*)alloc((size_t)DHB * (NNODES / 2) * 4);   // 6.4 MB
    int*   deg_out = (int*)alloc(NNODES * 4);
    int*   row_ptr = (int*)alloc((NNODES + 1) * 4);
    u16*   Wp1     = (u16*)alloc(256 * 128 * 2);
    u16*   Wp2     = (u16*)alloc(128 * 64 * 2);
    u16*   h       = (u16*)alloc((size_t)NNODES * 128 * 2);
    u16*   h1      = (u16*)alloc((size_t)NNODES * 128 * 2);
    u16*   h2      = (u16*)alloc((size_t)NNODES * 64 * 2);

    int nE = NEDGES;
    void* kargs[] = { (void*)&W1, (void*)&W2, (void*)&Wp1, (void*)&Wp2, (void*)&src, (void*)&dst,
                      (void*)&histg, (void*)&gh1, (void*)&scan1, (void*)&part1, (void*)&sbuf,
                      (void*)&gh2, (void*)&scan2g, (void*)&part2, (void*)&sorted,
                      (void*)&deg_out, (void*)&row_ptr, (void*)&nE };
    // 1: entire graph build (deg hist + 2-pass stable sort + bounds + weight prep)
    hipLaunchCooperativeKernel((void*)build_graph, dim3(NB), dim3(256), kargs, 0, stream);

    // 2-5: dense pipeline
    gemm_scaled<256, 128, true><<<(NNODES + 63) / 64, 256, 0, stream>>>(x, Wp1, deg_out, h, NNODES);
    gather1<<<(NNODES * 16 + 255) / 256, 256, 0, stream>>>((const uint4*)h, row_ptr, sorted, b1,
                                                           (uint4*)h1, NNODES);
    gemm_scaled<128, 64, false><<<(NNODES + 63) / 64, 256, 0, stream>>>(h1, Wp2, deg_out, h2, NNODES);
    gather2<<<(NNODES * 8 + 255) / 256, 256, 0, stream>>>((const uint4*)h2, row_ptr, sorted, b2, Wf, bfv,
                                                          out_logits, out_hidden, NNODES);
}

// Round 13
// 217.195 us; speedup vs baseline: 2.0466x; 2.0466x over previous
//
#include <hip/hip_runtime.h>
#include <hip/hip_bf16.h>
#include <cstdint>
#include <cstddef>

#define NNODES 50000
#define NEDGES 800000
// degree histogram: blocks 0..63 of pre_kernel
#define DHB    64
#define DHC    12500                       // 64*12500 = 800000
// pass-1 partition by dst>>8: 256 chunks x 3125 edges, 256 digit rows (196 used)
#define NCH    256
#define CHUNK1 3125                        // 256*3125 = 800000 exact
#define NBUCK  196                         // ceil(50000/256)

typedef unsigned short u16;
typedef unsigned int u32;
typedef short bfrag8 __attribute__((ext_vector_type(8)));
typedef float f32x4 __attribute__((ext_vector_type(4)));

__device__ __forceinline__ u16 f2bf(float f) {
    union { float f; uint32_t i; } v; v.f = f;
    uint32_t r = (v.i + 0x7FFFu + ((v.i >> 16) & 1u)) >> 16;
    return (u16)r;
}
__device__ __forceinline__ float bflo(u32 p) { union { uint32_t i; float f; } v; v.i = p << 16; return v.f; }
__device__ __forceinline__ float bfhi(u32 p) { union { uint32_t i; float f; } v; v.i = p & 0xFFFF0000u; return v.f; }

// ===== launch 1: deg hist (blocks 0..63) | partition hist by dst>>8 (64..319) | weight prep (320..447) =====
__global__ __launch_bounds__(256) void pre_kernel(const float* __restrict__ W1, const float* __restrict__ W2,
                                                  u16* __restrict__ P1, u16* __restrict__ P2,
                                                  const int* __restrict__ src, const int* __restrict__ dst,
                                                  u32* __restrict__ histg, u32* __restrict__ gh1, int nE) {
    __shared__ u32 hh[NNODES / 2];         // 100 KB
    int b = blockIdx.x, t = threadIdx.x;
    if (b < DHB) {
        for (int j = t; j < NNODES / 2; j += 256) hh[j] = 0;
        __syncthreads();
        int beg = b * DHC, end = min(beg + DHC, nE);
        for (int i = beg + t; i < end; i += 256) {
            u32 n = (u32)src[i];
            atomicAdd(&hh[n >> 1], 1u << ((n & 1) * 16));
        }
        __syncthreads();
        u32* out = histg + (size_t)b * (NNODES / 2);
        for (int j = t; j < NNODES / 2; j += 256) out[j] = hh[j];
    } else if (b < DHB + NCH) {
        int c = b - DHB;
        hh[t] = 0;
        __syncthreads();
        int beg = c * CHUNK1, end = min(beg + CHUNK1, nE);
        for (int i = beg + t; i < end; i += 256)
            atomicAdd(&hh[(u32)dst[i] >> 8], 1);
        __syncthreads();
        gh1[t * NCH + c] = hh[t];          // gh1[digit][chunk]
    } else {
        int i = (b - DHB - NCH) * 256 + t;
        if (i < 256 * 128) {
            int k = i >> 7, n = i & 127;
            P1[((((k >> 3) << 7) + n) << 3) | (k & 7)] = f2bf(W1[i]);
        }
        if (i < 128 * 64) {
            int k = i >> 6, n = i & 63;
            P2[((((k >> 3) << 6) + n) << 3) | (k & 7)] = f2bf(W2[i]);
        }
    }
}

// ===== launch 2: deg reduce + per-digit-row inclusive scan of gh1 (grid = 256) =====
__global__ __launch_bounds__(256) void red_scan1(const u32* __restrict__ histg, int* __restrict__ deg,
                                                 const u32* __restrict__ gh1, int* __restrict__ scan1,
                                                 int* __restrict__ part1) {
    int t = threadIdx.x, b = blockIdx.x;
    int n = b * 196 + t;
    if (t < 196 && n < NNODES) {
        int s = 0;
        #pragma unroll 4
        for (int bb = 0; bb < DHB; bb++)
            s += (int)((histg[(size_t)bb * (NNODES / 2) + (n >> 1)] >> ((n & 1) * 16)) & 0xFFFFu);
        deg[n] = s;
    }
    __shared__ int sd[256];
    int gi = b * NCH + t;                  // digit row b, chunk t
    int v = (int)gh1[gi];
    sd[t] = v;
    __syncthreads();
    #pragma unroll
    for (int o = 1; o < 256; o <<= 1) {
        int add = (t >= o) ? sd[t - o] : 0;
        __syncthreads();
        sd[t] += add;
        __syncthreads();
    }
    scan1[gi] = sd[t];
    if (t == 255) part1[b] = sd[255];      // digit b total
}

// ===== launch 3: partition scatter (grid = 256 chunks); digit offsets re-scanned in-block =====
__global__ __launch_bounds__(256) void scatter1(const int* __restrict__ dst, const int* __restrict__ src,
                                                const u32* __restrict__ gh1, const int* __restrict__ scan1,
                                                const int* __restrict__ part1, u32* __restrict__ sbuf, int nE) {
    __shared__ int sd[256];
    __shared__ int offs[256];
    __shared__ u32 base[256];
    __shared__ u32 lh[256];
    int t = threadIdx.x, c = blockIdx.x;
    int v = part1[t];
    sd[t] = v;
    __syncthreads();
    #pragma unroll
    for (int o = 1; o < 256; o <<= 1) {
        int add = (t >= o) ? sd[t - o] : 0;
        __syncthreads();
        sd[t] += add;
        __syncthreads();
    }
    offs[t] = sd[t] - v;                   // digit-level exclusive
    __syncthreads();
    base[t] = (u32)(scan1[t * NCH + c] + offs[t] - (int)gh1[t * NCH + c]);
    lh[t] = 0;
    __syncthreads();
    int beg = c * CHUNK1, end = min(beg + CHUNK1, nE);
    for (int i = beg + t; i < end; i += 256) {
        u32 el = ((u32)dst[i] << 16) | (u32)src[i];
        u32 d = el >> 24;                  // dst>>8
        u32 r = atomicAdd(&lh[d], 1);
        sbuf[base[d] + r] = el;
    }
}

// ===== launch 4: per-bucket LDS counting sort + row_ptr (grid = 196; replaces hist2/scan2/scatter2/bounds) =====
__global__ __launch_bounds__(256) void sort_bucket(const u32* __restrict__ sbuf, const int* __restrict__ part1,
                                                   u32* __restrict__ sorted, int* __restrict__ rp, int nE) {
    __shared__ int sd[256];
    __shared__ int cnt[256];
    __shared__ int cursor[256];
    int t = threadIdx.x, b = blockIdx.x;
    // bucket bounds from digit totals
    int v = part1[t];
    sd[t] = v;
    __syncthreads();
    #pragma unroll
    for (int o = 1; o < 256; o <<= 1) {
        int add = (t >= o) ? sd[t - o] : 0;
        __syncthreads();
        sd[t] += add;
        __syncthreads();
    }
    __shared__ int bs_s, bl_s;
    if (t == b) { bs_s = sd[t] - v; bl_s = v; }
    __syncthreads();
    int bstart = bs_s, bend = bstart + bl_s;
    // sweep 1: count low bytes
    cnt[t] = 0;
    __syncthreads();
    for (int i = bstart + t; i < bend; i += 256)
        atomicAdd(&cnt[(sbuf[i] >> 16) & 255u], 1);
    __syncthreads();
    // scan counts -> row_ptr + cursors
    int cv = cnt[t];
    sd[t] = cv;
    __syncthreads();
    #pragma unroll
    for (int o = 1; o < 256; o <<= 1) {
        int add = (t >= o) ? sd[t - o] : 0;
        __syncthreads();
        sd[t] += add;
        __syncthreads();
    }
    int excl = sd[t] - cv;
    int node = b * 256 + t;
    if (node < NNODES) rp[node] = bstart + excl;
    if (b == NBUCK - 1 && t == 0) rp[NNODES] = nE;
    cursor[t] = excl;
    __syncthreads();
    // sweep 2: place (unstable within node — aggregation is commutative)
    for (int i = bstart + t; i < bend; i += 256) {
        u32 el = sbuf[i];
        int r = atomicAdd(&cursor[(el >> 16) & 255u], 1);
        sorted[bstart + r] = el;
    }
}

// ============ dense compute (verified r8-r11) ============

template <int K, int N, bool AF32>
__global__ __launch_bounds__(256) void gemm_scaled(const void* __restrict__ A_, const u16* __restrict__ Wp,
                                                   const int* __restrict__ deg, u16* __restrict__ out, int M) {
    const int lane = threadIdx.x & 63;
    const int wave = threadIdx.x >> 6;
    const int m = lane & 15;
    const int q = lane >> 4;
    const int row0 = blockIdx.x * 64 + wave * 16;

    int rowa = row0 + m; if (rowa > M - 1) rowa = M - 1;

    constexpr int NT = N / 16;
    f32x4 acc[NT];
    #pragma unroll
    for (int t = 0; t < NT; t++) acc[t] = (f32x4){0.f, 0.f, 0.f, 0.f};

    #pragma unroll
    for (int kc = 0; kc < K; kc += 32) {
        bfrag8 af;
        if constexpr (AF32) {
            const float* ap = (const float*)A_ + (size_t)rowa * K + q * 8 + kc;
            const float4 x0 = *(const float4*)(ap);
            const float4 x1 = *(const float4*)(ap + 4);
            af[0] = (short)f2bf(x0.x); af[1] = (short)f2bf(x0.y);
            af[2] = (short)f2bf(x0.z); af[3] = (short)f2bf(x0.w);
            af[4] = (short)f2bf(x1.x); af[5] = (short)f2bf(x1.y);
            af[6] = (short)f2bf(x1.z); af[7] = (short)f2bf(x1.w);
        } else {
            const u16* ap = (const u16*)A_ + (size_t)rowa * K + q * 8 + kc;
            af = *(const bfrag8*)ap;
        }
        const u16* bbase = Wp + ((size_t)(((kc >> 3) + q) * N) + m) * 8;
        #pragma unroll
        for (int t = 0; t < NT; t++) {
            bfrag8 bf_ = *(const bfrag8*)(bbase + t * 128);
            acc[t] = __builtin_amdgcn_mfma_f32_16x16x32_bf16(af, bf_, acc[t], 0, 0, 0);
        }
    }
    #pragma unroll
    for (int r = 0; r < 4; r++) {
        int gr = row0 + q * 4 + r;
        if (gr < M) {
            int dO = deg[gr]; if (dO < 1) dO = 1;
            float s = rsqrtf((float)dO);
            #pragma unroll
            for (int t = 0; t < NT; t++)
                out[(size_t)gr * N + t * 16 + m] = f2bf(acc[t][r] * s);
        }
    }
}

// ---- layer-1 gather: quarter-wave (16 lanes x 16B) per node, unroll-8 ----
__global__ __launch_bounds__(256) void gather1(const uint4* __restrict__ h, const int* __restrict__ row_ptr,
                                               const u32* __restrict__ sorted, const float* __restrict__ b1,
                                               uint4* __restrict__ h1out, int nNodes) {
    int node = (blockIdx.x * 256 + threadIdx.x) >> 4;
    int l = threadIdx.x & 15;
    if (node >= nNodes) return;
    int beg = row_ptr[node], end = row_ptr[node + 1];
    float a[8] = {0.f, 0.f, 0.f, 0.f, 0.f, 0.f, 0.f, 0.f};
    for (int e = beg; e < end; e += 8) {
        uint4 p[8];
        #pragma unroll
        for (int j = 0; j < 8; j++) {
            int ee = e + j; ee = (ee < end - 1) ? ee : end - 1;
            p[j] = h[(size_t)(sorted[ee] & 0xFFFFu) * 16 + l];
        }
        #pragma unroll
        for (int j = 0; j < 8; j++)
            if (e + j < end) {
                a[0] += bflo(p[j].x); a[1] += bfhi(p[j].x);
                a[2] += bflo(p[j].y); a[3] += bfhi(p[j].y);
                a[4] += bflo(p[j].z); a[5] += bfhi(p[j].z);
                a[6] += bflo(p[j].w); a[7] += bfhi(p[j].w);
            }
    }
    int dI = end - beg; if (dI < 1) dI = 1;
    float r = rsqrtf((float)dI);
    const float4 bA = *(const float4*)(b1 + 8 * l);
    const float4 bB = *(const float4*)(b1 + 8 * l + 4);
    float v0 = fmaxf(a[0] * r + bA.x, 0.f), v1 = fmaxf(a[1] * r + bA.y, 0.f);
    float v2 = fmaxf(a[2] * r + bA.z, 0.f), v3 = fmaxf(a[3] * r + bA.w, 0.f);
    float v4 = fmaxf(a[4] * r + bB.x, 0.f), v5 = fmaxf(a[5] * r + bB.y, 0.f);
    float v6 = fmaxf(a[6] * r + bB.z, 0.f), v7 = fmaxf(a[7] * r + bB.w, 0.f);
    uint4 o;
    o.x = ((u32)f2bf(v1) << 16) | f2bf(v0);
    o.y = ((u32)f2bf(v3) << 16) | f2bf(v2);
    o.z = ((u32)f2bf(v5) << 16) | f2bf(v4);
    o.w = ((u32)f2bf(v7) << 16) | f2bf(v6);
    h1out[(size_t)node * 16 + l] = o;
}

// ---- layer-2 gather + projection: eighth-wave (8 lanes x 16B) per node, unroll-8 ----
__global__ __launch_bounds__(256) void gather2(const uint4* __restrict__ h2, const int* __restrict__ row_ptr,
                                               const u32* __restrict__ sorted, const float* __restrict__ b2,
                                               const float* __restrict__ Wf, const float* __restrict__ bfv,
                                               float* __restrict__ logits, float* __restrict__ hidden, int nNodes) {
    int node = (blockIdx.x * 256 + threadIdx.x) >> 3;
    int l = threadIdx.x & 7;
    if (node >= nNodes) return;
    int beg = row_ptr[node], end = row_ptr[node + 1];
    float a[8] = {0.f, 0.f, 0.f, 0.f, 0.f, 0.f, 0.f, 0.f};
    for (int e = beg; e < end; e += 8) {
        uint4 p[8];
        #pragma unroll
        for (int j = 0; j < 8; j++) {
            int ee = e + j; ee = (ee < end - 1) ? ee : end - 1;
            p[j] = h2[(size_t)(sorted[ee] & 0xFFFFu) * 8 + l];
        }
        #pragma unroll
        for (int j = 0; j < 8; j++)
            if (e + j < end) {
                a[0] += bflo(p[j].x); a[1] += bfhi(p[j].x);
                a[2] += bflo(p[j].y); a[3] += bfhi(p[j].y);
                a[4] += bflo(p[j].z); a[5] += bfhi(p[j].z);
                a[6] += bflo(p[j].w); a[7] += bfhi(p[j].w);
            }
    }
    int dI = end - beg; if (dI < 1) dI = 1;
    float r = rsqrtf((float)dI);
    float v[8];
    #pragma unroll
    for (int f = 0; f < 8; f++) v[f] = a[f] * r + b2[8 * l + f];
    float4 oA = {v[0], v[1], v[2], v[3]};
    float4 oB = {v[4], v[5], v[6], v[7]};
    ((float4*)hidden)[(size_t)node * 16 + 2 * l + 0] = oA;
    ((float4*)hidden)[(size_t)node * 16 + 2 * l + 1] = oB;
    float l0 = 0.f, l1 = 0.f;
    #pragma unroll
    for (int f = 0; f < 8; f++) {
        l0 += v[f] * Wf[(8 * l + f) * 2 + 0];
        l1 += v[f] * Wf[(8 * l + f) * 2 + 1];
    }
    #pragma unroll
    for (int off = 4; off > 0; off >>= 1) {
        l0 += __shfl_down(l0, off, 8);
        l1 += __shfl_down(l1, off, 8);
    }
    if (l == 0) {
        logits[(size_t)node * 2 + 0] = l0 + bfv[0];
        logits[(size_t)node * 2 + 1] = l1 + bfv[1];
    }
}

extern "C" void kernel_launch(void* const* d_in, const int* in_sizes, int n_in,
                              void* d_out, int out_size, void* d_ws, size_t ws_size,
                              hipStream_t stream) {
    const float* x   = (const float*)d_in[0];
    const float* W1  = (const float*)d_in[1];
    const float* b1  = (const float*)d_in[2];
    const float* W2  = (const float*)d_in[3];
    const float* b2  = (const float*)d_in[4];
    const float* Wf  = (const float*)d_in[5];
    const float* bfv = (const float*)d_in[6];
    const int* src = (const int*)d_in[7];
    const int* dst = (const int*)d_in[8];

    float* out_logits = (float*)d_out;
    float* out_hidden = (float*)d_out + 2 * NNODES;

    char* ws = (char*)d_ws;
    size_t off = 0;
    auto alloc = [&](size_t bytes) { void* p = ws + off; off += (bytes + 255) & ~(size_t)255; return p; };
    u32*   gh1     = (u32*)alloc(NCH * NCH * 4);            // 256 KB
    int*   scan1   = (int*)alloc(NCH * NCH * 4);
    int*   part1   = (int*)alloc(256 * 4);
    u32*   sbuf    = (u32*)alloc((size_t)NEDGES * 4);
    u32*   sorted  = (u32*)alloc((size_t)NEDGES * 4);
    u32*   histg   = (u32*)alloc((size_t)DHB * (NNODES / 2) * 4);   // 6.4 MB
    int*   deg_out = (int*)alloc(NNODES * 4);
    int*   row_ptr = (int*)alloc((NNODES + 1) * 4);
    u16*   Wp1     = (u16*)alloc(256 * 128 * 2);
    u16*   Wp2     = (u16*)alloc(128 * 64 * 2);
    u16*   h       = (u16*)alloc((size_t)NNODES * 128 * 2);
    u16*   h1      = (u16*)alloc((size_t)NNODES * 128 * 2);
    u16*   h2      = (u16*)alloc((size_t)NNODES * 64 * 2);

    // 1: deg hist + partition hist (dst>>8) + weight prep
    pre_kernel<<<DHB + NCH + 128, 256, 0, stream>>>(W1, W2, Wp1, Wp2, src, dst, histg, gh1, NEDGES);
    // 2: deg reduce + per-digit scan
    red_scan1<<<NCH, 256, 0, stream>>>(histg, deg_out, gh1, scan1, part1);
    // 3: partition into 196 dst-range buckets
    scatter1<<<NCH, 256, 0, stream>>>(dst, src, gh1, scan1, part1, sbuf, NEDGES);
    // 4: per-bucket counting sort + row_ptr  (replaces hist2+scan2+scatter2+bounds)
    sort_bucket<<<NBUCK, 256, 0, stream>>>(sbuf, part1, sorted, row_ptr, NEDGES);
    // 5-8: dense pipeline
    gemm_scaled<256, 128, true><<<(NNODES + 63) / 64, 256, 0, stream>>>(x, Wp1, deg_out, h, NNODES);
    gather1<<<(NNODES * 16 + 255) / 256, 256, 0, stream>>>((const uint4*)h, row_ptr, sorted, b1,
                                                           (uint4*)h1, NNODES);
    gemm_scaled<128, 64, false><<<(NNODES + 63) / 64, 256, 0, stream>>>(h1, Wp2, deg_out, h2, NNODES);
    gather2<<<(NNODES * 8 + 255) / 256, 256, 0, stream>>>((const uint4*)h2, row_ptr, sorted, b2, Wf, bfv,
                                                          out_logits, out_hidden, NNODES);
}